// Round 5
// baseline (413.335 us; speedup 1.0000x reference)
//
#include <hip/hip_runtime.h>
#include <hip/hip_bf16.h>

typedef __attribute__((ext_vector_type(4))) float f32x4;
typedef __attribute__((ext_vector_type(8))) short short8;

#define HH 512
#define BB 32
#define SS 2048
#define KK 1024  // 2H

__device__ __forceinline__ unsigned short f2bf(float f) {
    unsigned int u = __float_as_uint(f);
    u += 0x7fffu + ((u >> 16) & 1u);
    return (unsigned short)(u >> 16);
}

__device__ __forceinline__ ushort4 pack4(float4 f) {
    ushort4 p;
    p.x = f2bf(f.x); p.y = f2bf(f.y); p.z = f2bf(f.z); p.w = f2bf(f.w);
    return p;
}

__device__ __forceinline__ float fast_tanh(float x) {
    float e = __expf(2.0f * x);
    return 1.0f - 2.0f / (e + 1.0f);
}

// async global->LDS DMA, 16 B per lane (dest = wave-uniform base + lane*16)
__device__ __forceinline__ void dma16(const float* g, float* l) {
    __builtin_amdgcn_global_load_lds(
        (__attribute__((address_space(1))) const void*)g,
        (__attribute__((address_space(3))) void*)l, 16, 0, 0);
}

#define FENCE() asm volatile("" ::: "memory")

// fp32x8 -> bf16x8 (RNE). Scalar casts lower to v_cvt_pk_bf16_f32.
__device__ __forceinline__ short8 cvt_bf8(f32x4 a0, f32x4 a1) {
    short8 o;
    #pragma unroll
    for (int i = 0; i < 4; ++i) {
        union { __hip_bfloat16 h; unsigned short u; } c0, c1;
        c0.h = __float2bfloat16(a0[i]);
        c1.h = __float2bfloat16(a1[i]);
        o[i]     = (short)c0.u;
        o[i + 4] = (short)c1.u;
    }
    return o;
}

// ---------------- kernel 1: spb[b][h] = output[b]·W_s[h] + b_attn[h] ----------------
__global__ __launch_bounds__(256)
void spb_kernel(const float* __restrict__ out_state,
                const float* __restrict__ W,
                const float* __restrict__ bias,
                float* __restrict__ spb) {
    int wave = threadIdx.x >> 6, lane = threadIdx.x & 63;
    int g = blockIdx.x * 4 + wave;       // 16384 (b,h) pairs
    int b = g >> 9, h = g & 511;
    const float* wr = W + (size_t)h * 1536;      // W_s row h
    const float* ov = out_state + b * HH;
    float4 w0 = *(const float4*)(wr + lane * 8);
    float4 w1 = *(const float4*)(wr + lane * 8 + 4);
    float4 o0 = *(const float4*)(ov + lane * 8);
    float4 o1 = *(const float4*)(ov + lane * 8 + 4);
    float d = w0.x * o0.x + w0.y * o0.y + w0.z * o0.z + w0.w * o0.w
            + w1.x * o1.x + w1.y * o1.y + w1.z * o1.z + w1.w * o1.w;
    d += __shfl_xor(d, 1); d += __shfl_xor(d, 2); d += __shfl_xor(d, 4);
    d += __shfl_xor(d, 8); d += __shfl_xor(d, 16); d += __shfl_xor(d, 32);
    if (lane == 0) spb[g] = d + bias[h];
}

// ------- kernel 2: W_e -> bf16, FRAG-MAJOR layout Wt[kt][g][lane][8] -------
// g = h>>4, lane = (q<<4)|(h&15), q = (k>>3)&3: a wave's B-frag read is
// 64 lanes x 16B contiguous. One kt tile = 16384 shorts (K=32 x all 512 h).
__global__ void wconv_kernel(const float* __restrict__ W, unsigned short* __restrict__ Wt) {
    int idx = blockIdx.x * 256 + threadIdx.x;   // 65536 threads, 8 elems each
    int e8 = idx * 8;
    int h = e8 >> 10;        // [0,512)
    int k = e8 & 1023;       // multiple of 8
    const float* src = W + (size_t)h * 1536 + 512 + k;
    float4 w0 = *(const float4*)src;
    float4 w1 = *(const float4*)(src + 4);
    int kt = k >> 5;
    int q  = (k >> 3) & 3;
    int g  = h >> 4;
    int r  = h & 15;
    int ln = (q << 4) | r;
    unsigned short* dst = Wt + (size_t)kt * 16384 + g * 512 + ln * 8;
    *(ushort4*)dst = pack4(w0);
    *(ushort4*)(dst + 4) = pack4(w1);
}

// ---------------- kernel 3: fused GEMM + tanh + v-dot -> scores[b][s] ----------------
// v5: v4b with the VMEM ISSUE ORDER fixed for in-order vmcnt retirement.
// Per eighth: [16 bf loads (L2), OLDEST] -> [8 A-DMAs for e+1 (HBM), NEWEST]
// -> 4 compute sub-steps. Compiler bf-waits (vmcnt 20/16/12/8) now retire only
// the L2-fast bf loads; the HBM DMAs sit at the queue tail untouched until the
// single end-of-eighth vmcnt(0), by which point they had a full eighth
// (~6200 cy) to complete. v4b interleaved bf/DMA per sub-step, so every
// bf-wait transitively stalled on a 2-sub-step-old HBM DMA (~140 us => this).
//   A: global_load_lds from PRE-SWIZZLED global source (m173); LDS linear for
//      the DMA, XOR-swizzled for b128 frag reads (uniform 8 words/bank = min).
//   B: frag-major Wt (L2-resident), 16 frags/eighth in registers (64 VGPR).
__global__ __launch_bounds__(512, 2)
void attn_gemm(const float* __restrict__ enc, const unsigned short* __restrict__ Wt,
               const float* __restrict__ spb, const float* __restrict__ vvec,
               float* __restrict__ scores) {
    __shared__ __align__(16) float Asm[2][16384];   // 2 x 64 KB: [128 rows][128 k] fp32

    const int tid = threadIdx.x;
    const int w = tid >> 6;
    const int lane = tid & 63;
    const int r = lane & 15;
    const int q = lane >> 4;
    const int b = blockIdx.x >> 4;          // 32 b x 16 s-tiles
    const int s0 = (blockIdx.x & 15) << 7;  // 128 rows per tile
    const int bS = b * SS + s0;

    // ---- A-DMA addressing: per sub-step, 2 DMAs cover rows {w*4+lhi, w*4+2+lhi} ----
    const int l32 = lane & 31, lhi = lane >> 5;
    const int rowA = w * 4 + lhi;
    const int rowB = w * 4 + 2 + lhi;
    // pre-swizzled global source: float offset in row-eighth = ((l32^(row&7))<<2)
    const float* aP0 = enc + (size_t)(bS + rowA) * KK + ((l32 ^ (rowA & 7)) << 2);
    const float* aP1 = enc + (size_t)(bS + rowB) * KK + ((l32 ^ (rowB & 7)) << 2);
    // LDS dest float index (per-lane ptr = wave-uniform base + lane*16B)
    const int ad0 = (w * 4) * 128 + lane * 4;
    const int ad1 = (w * 4 + 2) * 128 + lane * 4;

    // ---- B frags: frag-major Wt, wave w covers col groups g = w*4+nf ----
    const short8* wp = (const short8*)(Wt + (size_t)(w * 4) * 512 + lane * 8);
    // + nf*64 (short8) per frag, + kt*2048 (short8) per K-tile

    // ---- A frag read constants (floats) ----
    const int ark = r & 7;        // row&7 for row = mt*16+r
    const int qb = q * 2;         // 16B-unit index base within k32 block
    const int arf = r * 128;      // + mt*2048 per mt

    f32x4 acc[8][4] = {};

    // ======== prologue: burst-stage eighth 0 (8 DMAs = 64KB/CU in flight) ========
    #pragma unroll
    for (int s = 0; s < 4; ++s) {
        dma16(aP0 + (size_t)s * 32 * KK, &Asm[0][s * 32 * 128 + ad0]);
        dma16(aP1 + (size_t)s * 32 * KK, &Asm[0][s * 32 * 128 + ad1]);
    }
    FENCE();
    asm volatile("s_waitcnt vmcnt(0)" ::: "memory");
    __builtin_amdgcn_s_barrier();
    __builtin_amdgcn_sched_barrier(0);

    // ======== main: eighths 0..6 (compute e from buf e&1, stage e+1 into other) ========
    for (int e = 0; e < 7; ++e) {
        const float* abase = &Asm[e & 1][0];
        float* sdst = &Asm[(e & 1) ^ 1][0];
        const size_t koff = (size_t)(e + 1) * 128;   // k offset of eighth e+1

        // --- 16 bf loads FIRST (oldest in FIFO; retire L2-fast) ---
        short8 bfr[4][4];
        #pragma unroll
        for (int kt2 = 0; kt2 < 4; ++kt2)
            #pragma unroll
            for (int nf = 0; nf < 4; ++nf)
                bfr[kt2][nf] = wp[(size_t)(e * 4 + kt2) * 2048 + nf * 64];
        FENCE();
        // --- 8 A-DMAs for eighth e+1 (newest; untouched until eighth end) ---
        #pragma unroll
        for (int s = 0; s < 4; ++s) {
            dma16(aP0 + koff + (size_t)s * 32 * KK, sdst + s * 32 * 128 + ad0);
            dma16(aP1 + koff + (size_t)s * 32 * KK, sdst + s * 32 * 128 + ad1);
        }
        FENCE();
        // --- compute: 4 sub-steps x 8 mt x 4 nf MFMA ---
        #pragma unroll
        for (int s = 0; s < 4; ++s) {
            const int u0 = ((s * 8 + qb) ^ ark) << 2;
            const int u1 = ((s * 8 + qb + 1) ^ ark) << 2;
            #pragma unroll
            for (int mt = 0; mt < 8; ++mt) {
                const int rowf = mt * 2048 + arf;
                f32x4 a0 = *(const f32x4*)(abase + rowf + u0);
                f32x4 a1 = *(const f32x4*)(abase + rowf + u1);
                short8 af = cvt_bf8(a0, a1);
                #pragma unroll
                for (int nf = 0; nf < 4; ++nf)
                    acc[mt][nf] = __builtin_amdgcn_mfma_f32_16x16x32_bf16(
                        af, bfr[s][nf], acc[mt][nf], 0, 0, 0);
            }
        }
        asm volatile("s_waitcnt vmcnt(0) lgkmcnt(0)" ::: "memory");
        __builtin_amdgcn_s_barrier();
        __builtin_amdgcn_sched_barrier(0);
    }

    // ======== peeled eighth 7: compute only (from buf 1) ========
    {
        const float* abase = &Asm[1][0];
        short8 bfr[4][4];
        #pragma unroll
        for (int kt2 = 0; kt2 < 4; ++kt2)
            #pragma unroll
            for (int nf = 0; nf < 4; ++nf)
                bfr[kt2][nf] = wp[(size_t)(28 + kt2) * 2048 + nf * 64];
        FENCE();
        #pragma unroll
        for (int s = 0; s < 4; ++s) {
            const int u0 = ((s * 8 + qb) ^ ark) << 2;
            const int u1 = ((s * 8 + qb + 1) ^ ark) << 2;
            #pragma unroll
            for (int mt = 0; mt < 8; ++mt) {
                const int rowf = mt * 2048 + arf;
                f32x4 a0 = *(const f32x4*)(abase + rowf + u0);
                f32x4 a1 = *(const f32x4*)(abase + rowf + u1);
                short8 af = cvt_bf8(a0, a1);
                #pragma unroll
                for (int nf = 0; nf < 4; ++nf)
                    acc[mt][nf] = __builtin_amdgcn_mfma_f32_16x16x32_bf16(
                        af, bfr[s][nf], acc[mt][nf], 0, 0, 0);
            }
        }
    }

    // ---- epilogue: partial score = sum over this wave's 64 cols of v[h]*tanh(.+spb)
    // red aliases Asm[0]: last Asm[0] reads were eighth 6, sealed by its barrier.
    float* red = (float*)&Asm[0][0];   // [8][128]
    float vh[4], sh[4];
    #pragma unroll
    for (int nf = 0; nf < 4; ++nf) {
        int h = w * 64 + nf * 16 + r;
        vh[nf] = vvec[h];
        sh[nf] = spb[b * HH + h];
    }
    float rowacc[8][4] = {};
    #pragma unroll
    for (int mt = 0; mt < 8; ++mt)
        #pragma unroll
        for (int nf = 0; nf < 4; ++nf)
            #pragma unroll
            for (int i = 0; i < 4; ++i) {
                float x = acc[mt][nf][i] + sh[nf];
                rowacc[mt][i] += vh[nf] * fast_tanh(x);
            }
    #pragma unroll
    for (int mt = 0; mt < 8; ++mt)
        #pragma unroll
        for (int i = 0; i < 4; ++i) {
            float t = rowacc[mt][i];
            t += __shfl_xor(t, 1);
            t += __shfl_xor(t, 2);
            t += __shfl_xor(t, 4);
            t += __shfl_xor(t, 8);
            rowacc[mt][i] = t;
        }
    __syncthreads();   // all acc reads of Asm done before red-store aliasing
    if (r == 0) {
        #pragma unroll
        for (int mt = 0; mt < 8; ++mt)
            #pragma unroll
            for (int i = 0; i < 4; ++i)
                red[w * 128 + mt * 16 + q * 4 + i] = rowacc[mt][i];
    }
    __syncthreads();
    if (tid < 128) {
        float sum = 0.f;
        #pragma unroll
        for (int ww = 0; ww < 8; ++ww) sum += red[ww * 128 + tid];
        scores[bS + tid] = sum;
    }
}

// ---------------- kernel 4: masked softmax over S per batch ----------------
__global__ void softmax_kernel(const float* __restrict__ scores,
                               const int* __restrict__ mask,
                               float* __restrict__ out) {
    __shared__ float red[256];
    int b = blockIdx.x, tid = threadIdx.x;
    float x[8];
    #pragma unroll
    for (int i = 0; i < 8; ++i) {
        int s = tid + i * 256;
        float sc = scores[b * SS + s];
        if (mask[b * SS + s] == 0) sc -= 1000.0f;
        x[i] = sc;
    }
    float mx = x[0];
    #pragma unroll
    for (int i = 1; i < 8; ++i) mx = fmaxf(mx, x[i]);
    red[tid] = mx;
    __syncthreads();
    for (int o = 128; o > 0; o >>= 1) {
        if (tid < o) red[tid] = fmaxf(red[tid], red[tid + o]);
        __syncthreads();
    }
    mx = red[0];
    __syncthreads();
    float e[8], sum = 0.f;
    #pragma unroll
    for (int i = 0; i < 8; ++i) { e[i] = __expf(x[i] - mx); sum += e[i]; }
    red[tid] = sum;
    __syncthreads();
    for (int o = 128; o > 0; o >>= 1) {
        if (tid < o) red[tid] += red[tid + o];
        __syncthreads();
    }
    float inv = 1.0f / red[0];
    #pragma unroll
    for (int i = 0; i < 8; ++i) out[b * SS + tid + i * 256] = e[i] * inv;
}

extern "C" void kernel_launch(void* const* d_in, const int* in_sizes, int n_in,
                              void* d_out, int out_size, void* d_ws, size_t ws_size,
                              hipStream_t stream) {
    const float* out_state = (const float*)d_in[0];   // (32, 512)
    const float* enc       = (const float*)d_in[1];   // (32, 2048, 1024)
    const int*   mask      = (const int*)d_in[2];     // (32, 2048)
    const float* W_attn    = (const float*)d_in[3];   // (512, 1536)
    const float* b_attn    = (const float*)d_in[4];   // (512,)
    const float* vvec      = (const float*)d_in[5];   // (512,)
    float* out = (float*)d_out;                       // (32, 1, 2048)

    char* ws = (char*)d_ws;
    float*          spb    = (float*)ws;                         // 64 KB
    unsigned short* Wt     = (unsigned short*)(ws + 65536);      // 1 MB
    float*          scores = (float*)(ws + 65536 + 1048576);     // 256 KB

    spb_kernel<<<4096, 256, 0, stream>>>(out_state, W_attn, b_attn, spb);
    wconv_kernel<<<256, 256, 0, stream>>>(W_attn, Wt);
    attn_gemm<<<512, 512, 0, stream>>>(enc, Wt, spb, vvec, scores);
    softmax_kernel<<<32, 256, 0, stream>>>(scores, mask, out);
}